// Round 7
// baseline (163.246 us; speedup 1.0000x reference)
//
#include <hip/hip_runtime.h>
#include <stdint.h>

#define BATCH 8
#define LTOK 1024
#define DMODEL 512
#define NHEAD 8
#define DHEAD 64

typedef unsigned short u16;
typedef u16 u16x8 __attribute__((ext_vector_type(8)));
typedef short bf16x8 __attribute__((ext_vector_type(8)));
typedef float f32x4 __attribute__((ext_vector_type(4)));

#define MFMA16(a,b,c) __builtin_amdgcn_mfma_f32_16x16x32_bf16((a),(b),(c),0,0,0)

__device__ __forceinline__ float bf2f(u16 x){
  union{unsigned u; float f;} v; v.u = ((unsigned)x)<<16; return v.f;
}
__device__ __forceinline__ u16 f2bf(float f){
  union{float f; unsigned u;} v; v.f = f;
  unsigned r = v.u + 0x7fffu + ((v.u>>16)&1u);
  return (u16)(r>>16);
}

__device__ __forceinline__ void gload_lds16(const u16* g, u16* l){
  __builtin_amdgcn_global_load_lds(
      (const __attribute__((address_space(1))) void*)g,
      (__attribute__((address_space(3))) void*)l,
      16, 0, 0);
}

// ---------------- fp32 -> bf16 elementwise convert ------------------------------
__global__ __launch_bounds__(256) void convert_k(const float* __restrict__ src,
                                                 u16* __restrict__ dst, int n){
  const int i = (blockIdx.x*256 + threadIdx.x)*8;
  if (i >= n) return;
  u16x8 v;
  #pragma unroll
  for (int j=0;j<8;j++) v[j] = f2bf(src[i+j]);
  *(u16x8*)(dst + i) = v;
}

// ---------------- 64x64 tiled transpose fp32->bf16: dst[c][r] = src[r][c] -------
__global__ __launch_bounds__(256) void transpose_f2b(const float* __restrict__ src,
                                                     u16* __restrict__ dst,
                                                     int R, int C){
  __shared__ __align__(16) u16 t[64][72];
  const int b  = blockIdx.z;
  const int r0 = blockIdx.x*64, c0 = blockIdx.y*64;
  const float* s = src + (size_t)b*R*C;
  u16* d         = dst + (size_t)b*R*C;
  const int tid = threadIdx.x;
  const int row = tid>>3, ch = (tid&7)*8;
  #pragma unroll
  for (int rr=0; rr<64; rr+=32){
    const float* p = s + (size_t)(r0+row+rr)*C + c0 + ch;
    u16x8 v;
    #pragma unroll
    for (int j=0;j<8;j++) v[j] = f2bf(p[j]);
    *(u16x8*)&t[row+rr][ch] = v;
  }
  __syncthreads();
  #pragma unroll
  for (int rr=0; rr<64; rr+=32){
    const int dr = row+rr;
    u16x8 v;
    #pragma unroll
    for (int j=0;j<8;j++) v[j] = t[ch+j][dr];
    *(u16x8*)(d + (size_t)(c0+dr)*R + r0 + ch) = v;
  }
}

// stage a 64x64 bf16 tile into linear LDS with the read-swizzle pre-applied to
// the source k-chunk (rule 21: filler granule (r, cc^(r&7)) holds A[r][cc*8])
__device__ __forceinline__ void stage_gemm(const u16* __restrict__ src,
                                           int row0, int k0, u16* lds, int tid){
  #pragma unroll
  for (int s2=0; s2<2; ++s2){
    const int slot = tid + s2*256;
    const int row = slot>>3, ch8 = slot&7;
    const int k = k0 + ((ch8 ^ (row&7))<<3);
    gload_lds16(src + (size_t)(row0+row)*DMODEL + k, lds + slot*8);
  }
}

// ---------------- QKV projection -> per-head qh[bh][l][d] and vt[bh][d][l] ------
__global__ __launch_bounds__(256) void qkv_gemm(const u16* __restrict__ A,
                                                const u16* __restrict__ W,
                                                u16* __restrict__ qh,
                                                u16* __restrict__ vt){
  __shared__ __align__(128) u16 sA[2][4096];
  __shared__ __align__(128) u16 sB[2][4096];
  const int m0 = blockIdx.x*64, n0 = blockIdx.y*64;
  const int tid = threadIdx.x, w = tid>>6, lane = tid&63;
  const int wr = w>>1, wc = w&1;
  const int lr = lane&15, lg = lane>>4;
  f32x4 acc[2][2] = {};
  stage_gemm(A, m0, 0, sA[0], tid);
  stage_gemm(W, n0, 0, sB[0], tid);
  int buf = 0;
  for (int kt=0; kt<8; ++kt){
    __syncthreads();
    if (kt < 7){
      stage_gemm(A, m0, (kt+1)*64, sA[buf^1], tid);
      stage_gemm(W, n0, (kt+1)*64, sB[buf^1], tid);
    }
    #pragma unroll
    for (int ks=0; ks<2; ++ks){
      bf16x8 af[2], bfr[2];
      #pragma unroll
      for (int mi=0; mi<2; ++mi){
        const int r = wr*32 + mi*16 + lr;
        af[mi] = *(const bf16x8*)(&sA[buf][(r*64 + ks*32 + lg*8) ^ ((r&7)<<3)]);
      }
      #pragma unroll
      for (int nj=0; nj<2; ++nj){
        const int r = wc*32 + nj*16 + lr;
        bfr[nj] = *(const bf16x8*)(&sB[buf][(r*64 + ks*32 + lg*8) ^ ((r&7)<<3)]);
      }
      #pragma unroll
      for (int mi=0; mi<2; ++mi)
        #pragma unroll
        for (int nj=0; nj<2; ++nj)
          acc[mi][nj] = MFMA16(af[mi], bfr[nj], acc[mi][nj]);
    }
    buf ^= 1;
  }
  #pragma unroll
  for (int mi=0; mi<2; ++mi)
    #pragma unroll
    for (int nj=0; nj<2; ++nj)
      #pragma unroll
      for (int r=0; r<4; ++r){
        const int m = m0 + wr*32 + mi*16 + lg*4 + r;
        const int n = n0 + wc*32 + nj*16 + lr;
        const int bb = m>>10, l = m&1023, hh = n>>6, d = n&63;
        const int bh = bb*NHEAD + hh;
        const u16 val = f2bf(acc[mi][nj][r]);
        qh[(size_t)bh*LTOK*DHEAD + (size_t)l*DHEAD + d] = val;
        vt[(size_t)bh*DHEAD*LTOK + (size_t)d*LTOK + l] = val;
      }
}

// ---------------- attention: barrier-free, K/V direct from L2, XCD-grouped ------
__global__ __launch_bounds__(256) void attn_k(const u16* __restrict__ qh,
                                              const u16* __restrict__ vt,
                                              u16* __restrict__ ao){
  __shared__ __align__(128) u16 sP[4096];     // 4 waves x wave-private 2KB
  const int bid = blockIdx.x;
  const int qt = bid >> 6, bh = bid & 63;     // XCD = bid%8 = bh%8 -> K/V L2-resident
  const int b = bh >> 3, h = bh & 7;
  const u16* Kb = qh + (size_t)bh*LTOK*DHEAD; // [l][d]
  const u16* Vb = vt + (size_t)bh*DHEAD*LTOK; // [d][l]
  const int tid = threadIdx.x, w = tid>>6, lane = tid&63;
  const int lr = lane&15, lg = lane>>4;
  const int wp = w*1024;                      // wave-private P region (u16 units)

  // Q fragment: rows qt*64 + w*16 + [0,16); scaled by (1/8)*log2(e)
  bf16x8 aq[2];
  {
    const int rq = qt*64 + w*16 + lr;
    #pragma unroll
    for (int ks=0; ks<2; ++ks){
      u16x8 v = *(const u16x8*)(Kb + (size_t)rq*DHEAD + ks*32 + lg*8);
      bf16x8 t;
      #pragma unroll
      for (int j=0;j<8;j++) t[j] = (short)f2bf(bf2f(v[j])*0.18033688f);
      aq[ks] = t;
    }
  }

  f32x4 o[4] = {};
  float lsum[4] = {0.f,0.f,0.f,0.f};

  for (int kt=0; kt<16; ++kt){
    // QK^T straight from global (L2-hit); scores already in log2-units
    f32x4 sc[4] = {};
    __builtin_amdgcn_s_setprio(1);
    #pragma unroll
    for (int ks=0; ks<2; ++ks){
      #pragma unroll
      for (int nj=0; nj<4; ++nj){
        const int rk = kt*64 + nj*16 + lr;
        bf16x8 bk = *(const bf16x8*)(Kb + (size_t)rk*DHEAD + ks*32 + lg*8);
        sc[nj] = MFMA16(aq[ks], bk, sc[nj]);
      }
    }
    __builtin_amdgcn_s_setprio(0);
    // p = exp2(sc), truncate to bf16 (sum the SAME truncated value -> no bias)
    #pragma unroll
    for (int nj=0; nj<4; ++nj){
      #pragma unroll
      for (int r=0; r<4; ++r){
        const float p = __builtin_amdgcn_exp2f(sc[nj][r]);
        const unsigned pu = __float_as_uint(p) & 0xFFFF0000u;
        lsum[r] += __uint_as_float(pu);
        const int prow = lg*4 + r;
        sP[wp + ((prow*64 + nj*16 + lr) ^ ((prow&7)<<3))] = (u16)(pu>>16);
      }
    }
    asm volatile("s_waitcnt lgkmcnt(0)" ::: "memory");
    // PV: P from wave-private LDS, V^T rows straight from global
    __builtin_amdgcn_s_setprio(1);
    #pragma unroll
    for (int ks=0; ks<2; ++ks){
      bf16x8 pa = *(const bf16x8*)(&sP[wp + ((lr*64 + ks*32 + lg*8) ^ ((lr&7)<<3))]);
      #pragma unroll
      for (int dj=0; dj<4; ++dj){
        const int d = dj*16 + lr;
        bf16x8 bv = *(const bf16x8*)(Vb + (size_t)d*LTOK + kt*64 + ks*32 + lg*8);
        o[dj] = MFMA16(pa, bv, o[dj]);
      }
    }
    __builtin_amdgcn_s_setprio(0);
  }

  // one deferred row-sum reduce across the 16 lanes sharing lg
  float inv[4];
  #pragma unroll
  for (int r=0; r<4; ++r){
    float s = lsum[r];
    s += __shfl_xor(s,1); s += __shfl_xor(s,2);
    s += __shfl_xor(s,4); s += __shfl_xor(s,8);
    inv[r] = __builtin_amdgcn_rcpf(s);
  }
  const int i0 = qt*64 + w*16;
  #pragma unroll
  for (int dj=0; dj<4; ++dj)
    #pragma unroll
    for (int r=0; r<4; ++r){
      const int l = i0 + lg*4 + r;
      const int d = dj*16 + lr;
      ao[((size_t)(b*LTOK + l))*DMODEL + h*DHEAD + d] = f2bf(o[dj][r]*inv[r]);
    }
}

// ---------------- FC projection + bias + residual -------------------------------
__global__ __launch_bounds__(256) void fc_gemm(const u16* __restrict__ A,
                                               const u16* __restrict__ W,
                                               const float* __restrict__ bias,
                                               const u16* __restrict__ resid,
                                               u16* __restrict__ Y){
  __shared__ __align__(128) u16 sA[2][4096];
  __shared__ __align__(128) u16 sB[2][4096];
  const int m0 = blockIdx.x*64, n0 = blockIdx.y*64;
  const int tid = threadIdx.x, w = tid>>6, lane = tid&63;
  const int wr = w>>1, wc = w&1;
  const int lr = lane&15, lg = lane>>4;
  f32x4 acc[2][2] = {};
  stage_gemm(A, m0, 0, sA[0], tid);
  stage_gemm(W, n0, 0, sB[0], tid);
  int buf = 0;
  for (int kt=0; kt<8; ++kt){
    __syncthreads();
    if (kt < 7){
      stage_gemm(A, m0, (kt+1)*64, sA[buf^1], tid);
      stage_gemm(W, n0, (kt+1)*64, sB[buf^1], tid);
    }
    #pragma unroll
    for (int ks=0; ks<2; ++ks){
      bf16x8 af[2], bfr[2];
      #pragma unroll
      for (int mi=0; mi<2; ++mi){
        const int r = wr*32 + mi*16 + lr;
        af[mi] = *(const bf16x8*)(&sA[buf][(r*64 + ks*32 + lg*8) ^ ((r&7)<<3)]);
      }
      #pragma unroll
      for (int nj=0; nj<2; ++nj){
        const int r = wc*32 + nj*16 + lr;
        bfr[nj] = *(const bf16x8*)(&sB[buf][(r*64 + ks*32 + lg*8) ^ ((r&7)<<3)]);
      }
      #pragma unroll
      for (int mi=0; mi<2; ++mi)
        #pragma unroll
        for (int nj=0; nj<2; ++nj)
          acc[mi][nj] = MFMA16(af[mi], bfr[nj], acc[mi][nj]);
    }
    buf ^= 1;
  }
  #pragma unroll
  for (int mi=0; mi<2; ++mi)
    #pragma unroll
    for (int nj=0; nj<2; ++nj)
      #pragma unroll
      for (int r=0; r<4; ++r){
        const int m = m0 + wr*32 + mi*16 + lg*4 + r;
        const int n = n0 + wc*32 + nj*16 + lr;
        const float val = acc[mi][nj][r] + bias[n] + bf2f(resid[(size_t)m*DMODEL+n]);
        Y[(size_t)m*DMODEL+n] = f2bf(val);
      }
}

// ---------------- LayerNorm over 512, one wave per row; fp32 out ----------------
__global__ __launch_bounds__(256) void ln_k(const u16* __restrict__ Y,
                                            const float* __restrict__ gamma,
                                            const float* __restrict__ beta,
                                            float* __restrict__ out){
  const int row = blockIdx.x*4 + (threadIdx.x>>6);
  const int lane = threadIdx.x&63;
  const u16* yr = Y + (size_t)row*DMODEL;
  u16x8 v = *(const u16x8*)(yr + lane*8);
  float x[8]; float s=0.f, sq=0.f;
  #pragma unroll
  for (int j=0;j<8;j++){ x[j]=bf2f(v[j]); s+=x[j]; sq+=x[j]*x[j]; }
  #pragma unroll
  for (int mk=1; mk<64; mk<<=1){ s += __shfl_xor(s,mk); sq += __shfl_xor(sq,mk); }
  const float mean = s*(1.f/DMODEL);
  float var = sq*(1.f/DMODEL) - mean*mean;
  const float rstd = rsqrtf(var + 1e-5f);
  float* po = out + (size_t)row*DMODEL + lane*8;
  #pragma unroll
  for (int j=0;j<8;j++){
    const int c = lane*8+j;
    po[j] = (x[j]-mean)*rstd*gamma[c] + beta[c];
  }
}

extern "C" void kernel_launch(void* const* d_in, const int* in_sizes, int n_in,
                              void* d_out, int out_size, void* d_ws, size_t ws_size,
                              hipStream_t stream){
  (void)in_sizes; (void)n_in; (void)out_size; (void)ws_size;
  const float* q      = (const float*)d_in[0];
  const float* w_qkvs = (const float*)d_in[1];
  const float* fc_w   = (const float*)d_in[2];
  const float* fc_b   = (const float*)d_in[3];
  const float* ln_g   = (const float*)d_in[4];
  const float* ln_b   = (const float*)d_in[5];
  float* out = (float*)d_out;
  char* ws = (char*)d_ws;
  u16* x_rm  = (u16*)(ws);                 // [8192][512] bf16
  u16* qh_sw = (u16*)(ws + 8388608);       // qh[bh][l][d] linear
  u16* vtt   = (u16*)(ws + 16777216);      // vt[bh][d][l] linear
  u16* ao    = (u16*)(ws + 25165824);      // [8192][512]
  u16* wqkvb = (u16*)(ws + 33554432);
  u16* wfcb  = (u16*)(ws + 34078720);
  u16* y0    = qh_sw;                      // reuse after attention

  convert_k<<<128,256,0,stream>>>(w_qkvs, wqkvb, DMODEL*DMODEL);
  convert_k<<<128,256,0,stream>>>(fc_w,   wfcb,  DMODEL*DMODEL);
  transpose_f2b<<<dim3(8,16,BATCH),256,0,stream>>>(q, x_rm, DMODEL, LTOK);
  qkv_gemm<<<dim3(128,8),256,0,stream>>>(x_rm, wqkvb, qh_sw, vtt);
  attn_k<<<1024,256,0,stream>>>(qh_sw, vtt, ao);
  fc_gemm<<<dim3(128,8),256,0,stream>>>(ao, wfcb, fc_b, x_rm, y0);
  ln_k<<<2048,256,0,stream>>>(y0, ln_g, ln_b, out);
}

// Round 8
// 85.977 us; speedup vs baseline: 1.8987x; 1.8987x over previous
//
#include <hip/hip_runtime.h>
#include <stdint.h>

#define BATCH 8
#define LTOK 1024
#define DMODEL 512
#define NHEAD 8
#define DHEAD 64

typedef unsigned short u16;
typedef u16 u16x8 __attribute__((ext_vector_type(8)));
typedef short bf16x8 __attribute__((ext_vector_type(8)));
typedef float f32x4 __attribute__((ext_vector_type(4)));

#define MFMA16(a,b,c) __builtin_amdgcn_mfma_f32_16x16x32_bf16((a),(b),(c),0,0,0)

__device__ __forceinline__ float bf2f(u16 x){
  union{unsigned u; float f;} v; v.u = ((unsigned)x)<<16; return v.f;
}
__device__ __forceinline__ u16 f2bf(float f){
  union{float f; unsigned u;} v; v.f = f;
  unsigned r = v.u + 0x7fffu + ((v.u>>16)&1u);
  return (u16)(r>>16);
}

__device__ __forceinline__ void gload_lds16(const u16* g, u16* l){
  __builtin_amdgcn_global_load_lds(
      (const __attribute__((address_space(1))) void*)g,
      (__attribute__((address_space(3))) void*)l,
      16, 0, 0);
}

// ---------------- fp32 -> bf16 elementwise convert ------------------------------
__global__ __launch_bounds__(256) void convert_k(const float* __restrict__ src,
                                                 u16* __restrict__ dst, int n){
  const int i = (blockIdx.x*256 + threadIdx.x)*8;
  if (i >= n) return;
  u16x8 v;
  #pragma unroll
  for (int j=0;j<8;j++) v[j] = f2bf(src[i+j]);
  *(u16x8*)(dst + i) = v;
}

// ---------------- 64x64 tiled transpose fp32->bf16: dst[c][r] = src[r][c] -------
__global__ __launch_bounds__(256) void transpose_f2b(const float* __restrict__ src,
                                                     u16* __restrict__ dst,
                                                     int R, int C){
  __shared__ __align__(16) u16 t[64][72];
  const int b  = blockIdx.z;
  const int r0 = blockIdx.x*64, c0 = blockIdx.y*64;
  const float* s = src + (size_t)b*R*C;
  u16* d         = dst + (size_t)b*R*C;
  const int tid = threadIdx.x;
  const int row = tid>>3, ch = (tid&7)*8;
  #pragma unroll
  for (int rr=0; rr<64; rr+=32){
    const float* p = s + (size_t)(r0+row+rr)*C + c0 + ch;
    u16x8 v;
    #pragma unroll
    for (int j=0;j<8;j++) v[j] = f2bf(p[j]);
    *(u16x8*)&t[row+rr][ch] = v;
  }
  __syncthreads();
  #pragma unroll
  for (int rr=0; rr<64; rr+=32){
    const int dr = row+rr;
    u16x8 v;
    #pragma unroll
    for (int j=0;j<8;j++) v[j] = t[ch+j][dr];
    *(u16x8*)(d + (size_t)(c0+dr)*R + r0 + ch) = v;
  }
}

// stage a 64x64 bf16 tile into linear LDS with the read-swizzle pre-applied to
// the source k-chunk (rule 21: filler granule (r, cc^(r&7)) holds A[r][cc*8])
__device__ __forceinline__ void stage_gemm(const u16* __restrict__ src,
                                           int row0, int k0, u16* lds, int tid){
  #pragma unroll
  for (int s2=0; s2<2; ++s2){
    const int slot = tid + s2*256;
    const int row = slot>>3, ch8 = slot&7;
    const int k = k0 + ((ch8 ^ (row&7))<<3);
    gload_lds16(src + (size_t)(row0+row)*DMODEL + k, lds + slot*8);
  }
}

// ---------------- QKV projection -> MFMA-fragment-major K/Q and V^T tiles -------
// Kf[bh][t][frag=ks*4+nj][lane=lg*16+lr][j]  holds K[t*64+nj*16+lr][ks*32+lg*8+j]
// Vf[bh][t][frag=ks*4+dj][lane=lg*16+lr][j]  holds V[t*64+ks*32+lg*8+j][dj*16+lr]
__global__ __launch_bounds__(256) void qkv_gemm(const u16* __restrict__ A,
                                                const u16* __restrict__ W,
                                                u16* __restrict__ Kf,
                                                u16* __restrict__ Vf){
  __shared__ __align__(128) u16 sA[2][4096];
  __shared__ __align__(128) u16 sB[2][4096];
  const int m0 = blockIdx.x*64, n0 = blockIdx.y*64;
  const int tid = threadIdx.x, w = tid>>6, lane = tid&63;
  const int wr = w>>1, wc = w&1;
  const int lr = lane&15, lg = lane>>4;
  f32x4 acc[2][2] = {};
  stage_gemm(A, m0, 0, sA[0], tid);
  stage_gemm(W, n0, 0, sB[0], tid);
  int buf = 0;
  for (int kt=0; kt<8; ++kt){
    __syncthreads();
    if (kt < 7){
      stage_gemm(A, m0, (kt+1)*64, sA[buf^1], tid);
      stage_gemm(W, n0, (kt+1)*64, sB[buf^1], tid);
    }
    #pragma unroll
    for (int ks=0; ks<2; ++ks){
      bf16x8 af[2], bfr[2];
      #pragma unroll
      for (int mi=0; mi<2; ++mi){
        const int r = wr*32 + mi*16 + lr;
        af[mi] = *(const bf16x8*)(&sA[buf][(r*64 + ks*32 + lg*8) ^ ((r&7)<<3)]);
      }
      #pragma unroll
      for (int nj=0; nj<2; ++nj){
        const int r = wc*32 + nj*16 + lr;
        bfr[nj] = *(const bf16x8*)(&sB[buf][(r*64 + ks*32 + lg*8) ^ ((r&7)<<3)]);
      }
      #pragma unroll
      for (int mi=0; mi<2; ++mi)
        #pragma unroll
        for (int nj=0; nj<2; ++nj)
          acc[mi][nj] = MFMA16(af[mi], bfr[nj], acc[mi][nj]);
    }
    buf ^= 1;
  }
  #pragma unroll
  for (int mi=0; mi<2; ++mi)
    #pragma unroll
    for (int nj=0; nj<2; ++nj)
      #pragma unroll
      for (int r=0; r<4; ++r){
        const int m = m0 + wr*32 + mi*16 + lg*4 + r;
        const int n = n0 + wc*32 + nj*16 + lr;
        const int bb = m>>10, l = m&1023, hh = n>>6, d = n&63;
        const int bh = bb*NHEAD + hh;
        const int t = l>>6;
        const u16 val = f2bf(acc[mi][nj][r]);
        {  // K/Q fragment position
          const int rr = l&63;
          const int fnj = rr>>4, flr = rr&15;
          const int fks = d>>5, flg = (d>>3)&3, fj = d&7;
          Kf[(size_t)(bh*16 + t)*4096 + (fks*4+fnj)*512 + (flg*16+flr)*8 + fj] = val;
        }
        {  // V fragment position
          const int ll = l&63;
          const int fks = ll>>5, flg = (ll>>3)&3, fj = ll&7;
          const int fdj = d>>4, flr = d&15;
          Vf[(size_t)(bh*16 + t)*4096 + (fks*4+fdj)*512 + (flg*16+flr)*8 + fj] = val;
        }
      }
}

// ---------------- attention: barrier-free, fragment-major K/V from L2 -----------
__global__ __launch_bounds__(256) void attn_k(const u16* __restrict__ kf,
                                              const u16* __restrict__ vf,
                                              u16* __restrict__ ao){
  __shared__ __align__(128) u16 sP[4096];     // 4 waves x wave-private 2KB
  const int bid = blockIdx.x;
  const int qt = bid >> 6, bh = bid & 63;     // XCD = bid%8 = bh%8 -> K/V L2-resident
  const int b = bh >> 3, h = bh & 7;
  const u16* Kf = kf + (size_t)bh*16*4096;
  const u16* Vf = vf + (size_t)bh*16*4096;
  const int tid = threadIdx.x, w = tid>>6, lane = tid&63;
  const int lr = lane&15, lg = lane>>4;
  const int wp = w*1024;                      // wave-private P region (u16 units)

  // Q fragment = K-fragment at tile qt, nj=w; scaled by (1/8)*log2(e)
  bf16x8 aq[2];
  #pragma unroll
  for (int ks=0; ks<2; ++ks){
    u16x8 v = *(const u16x8*)(Kf + (size_t)qt*4096 + (ks*4+w)*512 + lane*8);
    bf16x8 t;
    #pragma unroll
    for (int j=0;j<8;j++) t[j] = (short)f2bf(bf2f(v[j])*0.18033688f);
    aq[ks] = t;
  }

  f32x4 o[4] = {};
  float lsum[4] = {0.f,0.f,0.f,0.f};

  for (int kt=0; kt<16; ++kt){
    const u16* Kt = Kf + (size_t)kt*4096;
    const u16* Vt = Vf + (size_t)kt*4096;
    // QK^T: fragment loads are lane-major -> one 1KB coalesced read each
    f32x4 sc[4] = {};
    __builtin_amdgcn_s_setprio(1);
    #pragma unroll
    for (int ks=0; ks<2; ++ks){
      #pragma unroll
      for (int nj=0; nj<4; ++nj){
        bf16x8 bk = *(const bf16x8*)(Kt + (ks*4+nj)*512 + lane*8);
        sc[nj] = MFMA16(aq[ks], bk, sc[nj]);
      }
    }
    __builtin_amdgcn_s_setprio(0);
    // p = exp2(sc), truncate to bf16 (sum the SAME truncated value -> no bias)
    #pragma unroll
    for (int nj=0; nj<4; ++nj){
      #pragma unroll
      for (int r=0; r<4; ++r){
        const float p = __builtin_amdgcn_exp2f(sc[nj][r]);
        const unsigned pu = __float_as_uint(p) & 0xFFFF0000u;
        lsum[r] += __uint_as_float(pu);
        const int prow = lg*4 + r;
        sP[wp + ((prow*64 + nj*16 + lr) ^ ((prow&7)<<3))] = (u16)(pu>>16);
      }
    }
    asm volatile("s_waitcnt lgkmcnt(0)" ::: "memory");
    // PV: P from wave-private LDS, V fragments coalesced from L2
    __builtin_amdgcn_s_setprio(1);
    #pragma unroll
    for (int ks=0; ks<2; ++ks){
      bf16x8 pa = *(const bf16x8*)(&sP[wp + ((lr*64 + ks*32 + lg*8) ^ ((lr&7)<<3))]);
      #pragma unroll
      for (int dj=0; dj<4; ++dj){
        bf16x8 bv = *(const bf16x8*)(Vt + (ks*4+dj)*512 + lane*8);
        o[dj] = MFMA16(pa, bv, o[dj]);
      }
    }
    __builtin_amdgcn_s_setprio(0);
  }

  // one deferred row-sum reduce across the 16 lanes sharing lg
  float inv[4];
  #pragma unroll
  for (int r=0; r<4; ++r){
    float s = lsum[r];
    s += __shfl_xor(s,1); s += __shfl_xor(s,2);
    s += __shfl_xor(s,4); s += __shfl_xor(s,8);
    inv[r] = __builtin_amdgcn_rcpf(s);
  }
  const int i0 = qt*64 + w*16;
  #pragma unroll
  for (int dj=0; dj<4; ++dj)
    #pragma unroll
    for (int r=0; r<4; ++r){
      const int l = i0 + lg*4 + r;
      const int d = dj*16 + lr;
      ao[((size_t)(b*LTOK + l))*DMODEL + h*DHEAD + d] = f2bf(o[dj][r]*inv[r]);
    }
}

// ---------------- FC projection + bias + residual -------------------------------
__global__ __launch_bounds__(256) void fc_gemm(const u16* __restrict__ A,
                                               const u16* __restrict__ W,
                                               const float* __restrict__ bias,
                                               const u16* __restrict__ resid,
                                               u16* __restrict__ Y){
  __shared__ __align__(128) u16 sA[2][4096];
  __shared__ __align__(128) u16 sB[2][4096];
  const int m0 = blockIdx.x*64, n0 = blockIdx.y*64;
  const int tid = threadIdx.x, w = tid>>6, lane = tid&63;
  const int wr = w>>1, wc = w&1;
  const int lr = lane&15, lg = lane>>4;
  f32x4 acc[2][2] = {};
  stage_gemm(A, m0, 0, sA[0], tid);
  stage_gemm(W, n0, 0, sB[0], tid);
  int buf = 0;
  for (int kt=0; kt<8; ++kt){
    __syncthreads();
    if (kt < 7){
      stage_gemm(A, m0, (kt+1)*64, sA[buf^1], tid);
      stage_gemm(W, n0, (kt+1)*64, sB[buf^1], tid);
    }
    #pragma unroll
    for (int ks=0; ks<2; ++ks){
      bf16x8 af[2], bfr[2];
      #pragma unroll
      for (int mi=0; mi<2; ++mi){
        const int r = wr*32 + mi*16 + lr;
        af[mi] = *(const bf16x8*)(&sA[buf][(r*64 + ks*32 + lg*8) ^ ((r&7)<<3)]);
      }
      #pragma unroll
      for (int nj=0; nj<2; ++nj){
        const int r = wc*32 + nj*16 + lr;
        bfr[nj] = *(const bf16x8*)(&sB[buf][(r*64 + ks*32 + lg*8) ^ ((r&7)<<3)]);
      }
      #pragma unroll
      for (int mi=0; mi<2; ++mi)
        #pragma unroll
        for (int nj=0; nj<2; ++nj)
          acc[mi][nj] = MFMA16(af[mi], bfr[nj], acc[mi][nj]);
    }
    buf ^= 1;
  }
  #pragma unroll
  for (int mi=0; mi<2; ++mi)
    #pragma unroll
    for (int nj=0; nj<2; ++nj)
      #pragma unroll
      for (int r=0; r<4; ++r){
        const int m = m0 + wr*32 + mi*16 + lg*4 + r;
        const int n = n0 + wc*32 + nj*16 + lr;
        const float val = acc[mi][nj][r] + bias[n] + bf2f(resid[(size_t)m*DMODEL+n]);
        Y[(size_t)m*DMODEL+n] = f2bf(val);
      }
}

// ---------------- LayerNorm over 512, one wave per row; fp32 out ----------------
__global__ __launch_bounds__(256) void ln_k(const u16* __restrict__ Y,
                                            const float* __restrict__ gamma,
                                            const float* __restrict__ beta,
                                            float* __restrict__ out){
  const int row = blockIdx.x*4 + (threadIdx.x>>6);
  const int lane = threadIdx.x&63;
  const u16* yr = Y + (size_t)row*DMODEL;
  u16x8 v = *(const u16x8*)(yr + lane*8);
  float x[8]; float s=0.f, sq=0.f;
  #pragma unroll
  for (int j=0;j<8;j++){ x[j]=bf2f(v[j]); s+=x[j]; sq+=x[j]*x[j]; }
  #pragma unroll
  for (int mk=1; mk<64; mk<<=1){ s += __shfl_xor(s,mk); sq += __shfl_xor(sq,mk); }
  const float mean = s*(1.f/DMODEL);
  float var = sq*(1.f/DMODEL) - mean*mean;
  const float rstd = rsqrtf(var + 1e-5f);
  float* po = out + (size_t)row*DMODEL + lane*8;
  #pragma unroll
  for (int j=0;j<8;j++){
    const int c = lane*8+j;
    po[j] = (x[j]-mean)*rstd*gamma[c] + beta[c];
  }
}

extern "C" void kernel_launch(void* const* d_in, const int* in_sizes, int n_in,
                              void* d_out, int out_size, void* d_ws, size_t ws_size,
                              hipStream_t stream){
  (void)in_sizes; (void)n_in; (void)out_size; (void)ws_size;
  const float* q      = (const float*)d_in[0];
  const float* w_qkvs = (const float*)d_in[1];
  const float* fc_w   = (const float*)d_in[2];
  const float* fc_b   = (const float*)d_in[3];
  const float* ln_g   = (const float*)d_in[4];
  const float* ln_b   = (const float*)d_in[5];
  float* out = (float*)d_out;
  char* ws = (char*)d_ws;
  u16* x_rm  = (u16*)(ws);                 // [8192][512] bf16
  u16* kfb   = (u16*)(ws + 8388608);       // fragment-major K/Q tiles
  u16* vfb   = (u16*)(ws + 16777216);      // fragment-major V tiles
  u16* ao    = (u16*)(ws + 25165824);      // [8192][512]
  u16* wqkvb = (u16*)(ws + 33554432);
  u16* wfcb  = (u16*)(ws + 34078720);
  u16* y0    = kfb;                        // reuse after attention

  convert_k<<<128,256,0,stream>>>(w_qkvs, wqkvb, DMODEL*DMODEL);
  convert_k<<<128,256,0,stream>>>(fc_w,   wfcb,  DMODEL*DMODEL);
  transpose_f2b<<<dim3(8,16,BATCH),256,0,stream>>>(q, x_rm, DMODEL, LTOK);
  qkv_gemm<<<dim3(128,8),256,0,stream>>>(x_rm, wqkvb, kfb, vfb);
  attn_k<<<1024,256,0,stream>>>(kfb, vfb, ao);
  fc_gemm<<<dim3(128,8),256,0,stream>>>(ao, wfcb, fc_b, x_rm, y0);
  ln_k<<<2048,256,0,stream>>>(y0, ln_g, ln_b, out);
}

// Round 9
// 81.666 us; speedup vs baseline: 1.9990x; 1.0528x over previous
//
#include <hip/hip_runtime.h>
#include <stdint.h>

#define BATCH 8
#define LTOK 1024
#define DMODEL 512
#define NHEAD 8
#define DHEAD 64

typedef unsigned short u16;
typedef u16 u16x8 __attribute__((ext_vector_type(8)));
typedef short bf16x8 __attribute__((ext_vector_type(8)));
typedef float f32x4 __attribute__((ext_vector_type(4)));

#define MFMA16(a,b,c) __builtin_amdgcn_mfma_f32_16x16x32_bf16((a),(b),(c),0,0,0)

__device__ __forceinline__ float bf2f(u16 x){
  union{unsigned u; float f;} v; v.u = ((unsigned)x)<<16; return v.f;
}
__device__ __forceinline__ u16 f2bf(float f){
  union{float f; unsigned u;} v; v.f = f;
  unsigned r = v.u + 0x7fffu + ((v.u>>16)&1u);
  return (u16)(r>>16);
}

__device__ __forceinline__ void gload_lds16(const u16* g, u16* l){
  __builtin_amdgcn_global_load_lds(
      (const __attribute__((address_space(1))) void*)g,
      (__attribute__((address_space(3))) void*)l,
      16, 0, 0);
}

// ---------------- fp32 -> bf16 elementwise convert ------------------------------
__global__ __launch_bounds__(256) void convert_k(const float* __restrict__ src,
                                                 u16* __restrict__ dst, int n){
  const int i = (blockIdx.x*256 + threadIdx.x)*8;
  if (i >= n) return;
  u16x8 v;
  #pragma unroll
  for (int j=0;j<8;j++) v[j] = f2bf(src[i+j]);
  *(u16x8*)(dst + i) = v;
}

// ---------------- 64x64 tiled transpose fp32->bf16: dst[c][r] = src[r][c] -------
__global__ __launch_bounds__(256) void transpose_f2b(const float* __restrict__ src,
                                                     u16* __restrict__ dst,
                                                     int R, int C){
  __shared__ __align__(16) u16 t[64][72];
  const int b  = blockIdx.z;
  const int r0 = blockIdx.x*64, c0 = blockIdx.y*64;
  const float* s = src + (size_t)b*R*C;
  u16* d         = dst + (size_t)b*R*C;
  const int tid = threadIdx.x;
  const int row = tid>>3, ch = (tid&7)*8;
  #pragma unroll
  for (int rr=0; rr<64; rr+=32){
    const float* p = s + (size_t)(r0+row+rr)*C + c0 + ch;
    u16x8 v;
    #pragma unroll
    for (int j=0;j<8;j++) v[j] = f2bf(p[j]);
    *(u16x8*)&t[row+rr][ch] = v;
  }
  __syncthreads();
  #pragma unroll
  for (int rr=0; rr<64; rr+=32){
    const int dr = row+rr;
    u16x8 v;
    #pragma unroll
    for (int j=0;j<8;j++) v[j] = t[ch+j][dr];
    *(u16x8*)(d + (size_t)(c0+dr)*R + r0 + ch) = v;
  }
}

// stage a 64x64 bf16 tile into linear LDS with the read-swizzle pre-applied to
// the source k-chunk (rule 21: filler granule (r, cc^(r&7)) holds A[r][cc*8])
__device__ __forceinline__ void stage_gemm(const u16* __restrict__ src,
                                           int row0, int k0, u16* lds, int tid){
  #pragma unroll
  for (int s2=0; s2<2; ++s2){
    const int slot = tid + s2*256;
    const int row = slot>>3, ch8 = slot&7;
    const int k = k0 + ((ch8 ^ (row&7))<<3);
    gload_lds16(src + (size_t)(row0+row)*DMODEL + k, lds + slot*8);
  }
}

// ---------------- QKV projection -> MFMA-fragment-major K/Q and V^T tiles -------
// Kf[bh][t][frag=ks*4+nj][lane=lg*16+lr][j]  holds K[t*64+nj*16+lr][ks*32+lg*8+j]
// Vf[bh][t][frag=ks*4+dj][lane=lg*16+lr][j]  holds V[t*64+ks*32+lg*8+j][dj*16+lr]
__global__ __launch_bounds__(256) void qkv_gemm(const u16* __restrict__ A,
                                                const u16* __restrict__ W,
                                                u16* __restrict__ Kf,
                                                u16* __restrict__ Vf){
  __shared__ __align__(128) u16 sA[2][4096];
  __shared__ __align__(128) u16 sB[2][4096];
  const int m0 = blockIdx.x*64, n0 = blockIdx.y*64;
  const int tid = threadIdx.x, w = tid>>6, lane = tid&63;
  const int wr = w>>1, wc = w&1;
  const int lr = lane&15, lg = lane>>4;
  f32x4 acc[2][2] = {};
  stage_gemm(A, m0, 0, sA[0], tid);
  stage_gemm(W, n0, 0, sB[0], tid);
  int buf = 0;
  for (int kt=0; kt<8; ++kt){
    __syncthreads();
    if (kt < 7){
      stage_gemm(A, m0, (kt+1)*64, sA[buf^1], tid);
      stage_gemm(W, n0, (kt+1)*64, sB[buf^1], tid);
    }
    #pragma unroll
    for (int ks=0; ks<2; ++ks){
      bf16x8 af[2], bfr[2];
      #pragma unroll
      for (int mi=0; mi<2; ++mi){
        const int r = wr*32 + mi*16 + lr;
        af[mi] = *(const bf16x8*)(&sA[buf][(r*64 + ks*32 + lg*8) ^ ((r&7)<<3)]);
      }
      #pragma unroll
      for (int nj=0; nj<2; ++nj){
        const int r = wc*32 + nj*16 + lr;
        bfr[nj] = *(const bf16x8*)(&sB[buf][(r*64 + ks*32 + lg*8) ^ ((r&7)<<3)]);
      }
      #pragma unroll
      for (int mi=0; mi<2; ++mi)
        #pragma unroll
        for (int nj=0; nj<2; ++nj)
          acc[mi][nj] = MFMA16(af[mi], bfr[nj], acc[mi][nj]);
    }
    buf ^= 1;
  }
  #pragma unroll
  for (int mi=0; mi<2; ++mi)
    #pragma unroll
    for (int nj=0; nj<2; ++nj)
      #pragma unroll
      for (int r=0; r<4; ++r){
        const int m = m0 + wr*32 + mi*16 + lg*4 + r;
        const int n = n0 + wc*32 + nj*16 + lr;
        const int bb = m>>10, l = m&1023, hh = n>>6, d = n&63;
        const int bh = bb*NHEAD + hh;
        const int t = l>>6;
        const u16 val = f2bf(acc[mi][nj][r]);
        {  // K/Q fragment position
          const int rr = l&63;
          const int fnj = rr>>4, flr = rr&15;
          const int fks = d>>5, flg = (d>>3)&3, fj = d&7;
          Kf[(size_t)(bh*16 + t)*4096 + (fks*4+fnj)*512 + (flg*16+flr)*8 + fj] = val;
        }
        {  // V fragment position
          const int ll = l&63;
          const int fks = ll>>5, flg = (ll>>3)&3, fj = ll&7;
          const int fdj = d>>4, flr = d&15;
          Vf[(size_t)(bh*16 + t)*4096 + (fks*4+fdj)*512 + (flg*16+flr)*8 + fj] = val;
        }
      }
}

// ---------------- attention: 64 q-rows/wave, frag-major K/V, barrier-free -------
__global__ __launch_bounds__(256,1) void attn_k(const u16* __restrict__ kf,
                                                const u16* __restrict__ vf,
                                                u16* __restrict__ ao){
  __shared__ __align__(128) u16 sP[16384];    // [wave][group] private 2KB regions
  const int bid = blockIdx.x;
  const int qt = bid >> 6, bh = bid & 63;     // XCD = bid%8 = bh%8 -> K/V L2-resident
  const int b = bh >> 3, h = bh & 7;
  const u16* Kf = kf + (size_t)bh*16*4096;
  const u16* Vf = vf + (size_t)bh*16*4096;
  const int tid = threadIdx.x, w = tid>>6, lane = tid&63;
  const int lr = lane&15, lg = lane>>4;
  const int qtw = qt*4 + w;                   // this wave's 64-row q-tile

  // Q fragments for 4 groups = the 4 nj-subtiles of q-tile qtw; pre-scaled
  bf16x8 aq[4][2];
  #pragma unroll
  for (int g=0; g<4; ++g)
    #pragma unroll
    for (int ks=0; ks<2; ++ks){
      u16x8 v = *(const u16x8*)(Kf + (size_t)qtw*4096 + (ks*4+g)*512 + lane*8);
      bf16x8 t;
      #pragma unroll
      for (int j=0;j<8;j++) t[j] = (short)f2bf(bf2f(v[j])*0.18033688f);
      aq[g][ks] = t;
    }

  f32x4 o[4][4] = {};
  float lsum[4][4] = {};

  for (int kt=0; kt<16; ++kt){
    const u16* Kt = Kf + (size_t)kt*4096;
    const u16* Vt = Vf + (size_t)kt*4096;
    // K fragments once, reused by all 4 q-groups
    bf16x8 bk[2][4];
    #pragma unroll
    for (int ks=0; ks<2; ++ks)
      #pragma unroll
      for (int nj=0; nj<4; ++nj)
        bk[ks][nj] = *(const bf16x8*)(Kt + (ks*4+nj)*512 + lane*8);
    #pragma unroll
    for (int g=0; g<4; ++g){
      f32x4 sc[4] = {};
      __builtin_amdgcn_s_setprio(1);
      #pragma unroll
      for (int ks=0; ks<2; ++ks)
        #pragma unroll
        for (int nj=0; nj<4; ++nj)
          sc[nj] = MFMA16(aq[g][ks], bk[ks][nj], sc[nj]);
      __builtin_amdgcn_s_setprio(0);
      const int wp = (w*4+g)*1024;
      #pragma unroll
      for (int nj=0; nj<4; ++nj){
        #pragma unroll
        for (int r=0; r<4; ++r){
          const float p = __builtin_amdgcn_exp2f(sc[nj][r]);
          const unsigned pu = __float_as_uint(p) & 0xFFFF0000u;
          lsum[g][r] += __uint_as_float(pu);
          const int prow = lg*4 + r;
          sP[wp + ((prow*64 + nj*16 + lr) ^ ((prow&7)<<3))] = (u16)(pu>>16);
        }
      }
    }
    asm volatile("s_waitcnt lgkmcnt(0)" ::: "memory");
    // V fragments once, reused by all 4 q-groups
    bf16x8 bv[2][4];
    #pragma unroll
    for (int ks=0; ks<2; ++ks)
      #pragma unroll
      for (int dj=0; dj<4; ++dj)
        bv[ks][dj] = *(const bf16x8*)(Vt + (ks*4+dj)*512 + lane*8);
    __builtin_amdgcn_s_setprio(1);
    #pragma unroll
    for (int g=0; g<4; ++g){
      const int wp = (w*4+g)*1024;
      #pragma unroll
      for (int ks=0; ks<2; ++ks){
        bf16x8 pa = *(const bf16x8*)(&sP[wp + ((lr*64 + ks*32 + lg*8) ^ ((lr&7)<<3))]);
        #pragma unroll
        for (int dj=0; dj<4; ++dj)
          o[g][dj] = MFMA16(pa, bv[ks][dj], o[g][dj]);
      }
    }
    __builtin_amdgcn_s_setprio(0);
  }

  // deferred row-sum reduce + write 64 rows
  #pragma unroll
  for (int g=0; g<4; ++g){
    float inv[4];
    #pragma unroll
    for (int r=0; r<4; ++r){
      float s = lsum[g][r];
      s += __shfl_xor(s,1); s += __shfl_xor(s,2);
      s += __shfl_xor(s,4); s += __shfl_xor(s,8);
      inv[r] = __builtin_amdgcn_rcpf(s);
    }
    const int i0 = qtw*64 + g*16;
    #pragma unroll
    for (int dj=0; dj<4; ++dj)
      #pragma unroll
      for (int r=0; r<4; ++r){
        const int l = i0 + lg*4 + r;
        const int d = dj*16 + lr;
        ao[((size_t)(b*LTOK + l))*DMODEL + h*DHEAD + d] = f2bf(o[g][dj][r]*inv[r]);
      }
  }
}

// ---------------- FC projection + bias + residual -------------------------------
__global__ __launch_bounds__(256) void fc_gemm(const u16* __restrict__ A,
                                               const u16* __restrict__ W,
                                               const float* __restrict__ bias,
                                               const u16* __restrict__ resid,
                                               u16* __restrict__ Y){
  __shared__ __align__(128) u16 sA[2][4096];
  __shared__ __align__(128) u16 sB[2][4096];
  const int m0 = blockIdx.x*64, n0 = blockIdx.y*64;
  const int tid = threadIdx.x, w = tid>>6, lane = tid&63;
  const int wr = w>>1, wc = w&1;
  const int lr = lane&15, lg = lane>>4;
  f32x4 acc[2][2] = {};
  stage_gemm(A, m0, 0, sA[0], tid);
  stage_gemm(W, n0, 0, sB[0], tid);
  int buf = 0;
  for (int kt=0; kt<8; ++kt){
    __syncthreads();
    if (kt < 7){
      stage_gemm(A, m0, (kt+1)*64, sA[buf^1], tid);
      stage_gemm(W, n0, (kt+1)*64, sB[buf^1], tid);
    }
    #pragma unroll
    for (int ks=0; ks<2; ++ks){
      bf16x8 af[2], bfr[2];
      #pragma unroll
      for (int mi=0; mi<2; ++mi){
        const int r = wr*32 + mi*16 + lr;
        af[mi] = *(const bf16x8*)(&sA[buf][(r*64 + ks*32 + lg*8) ^ ((r&7)<<3)]);
      }
      #pragma unroll
      for (int nj=0; nj<2; ++nj){
        const int r = wc*32 + nj*16 + lr;
        bfr[nj] = *(const bf16x8*)(&sB[buf][(r*64 + ks*32 + lg*8) ^ ((r&7)<<3)]);
      }
      #pragma unroll
      for (int mi=0; mi<2; ++mi)
        #pragma unroll
        for (int nj=0; nj<2; ++nj)
          acc[mi][nj] = MFMA16(af[mi], bfr[nj], acc[mi][nj]);
    }
    buf ^= 1;
  }
  #pragma unroll
  for (int mi=0; mi<2; ++mi)
    #pragma unroll
    for (int nj=0; nj<2; ++nj)
      #pragma unroll
      for (int r=0; r<4; ++r){
        const int m = m0 + wr*32 + mi*16 + lg*4 + r;
        const int n = n0 + wc*32 + nj*16 + lr;
        const float val = acc[mi][nj][r] + bias[n] + bf2f(resid[(size_t)m*DMODEL+n]);
        Y[(size_t)m*DMODEL+n] = f2bf(val);
      }
}

// ---------------- LayerNorm over 512, one wave per row; fp32 out ----------------
__global__ __launch_bounds__(256) void ln_k(const u16* __restrict__ Y,
                                            const float* __restrict__ gamma,
                                            const float* __restrict__ beta,
                                            float* __restrict__ out){
  const int row = blockIdx.x*4 + (threadIdx.x>>6);
  const int lane = threadIdx.x&63;
  const u16* yr = Y + (size_t)row*DMODEL;
  u16x8 v = *(const u16x8*)(yr + lane*8);
  float x[8]; float s=0.f, sq=0.f;
  #pragma unroll
  for (int j=0;j<8;j++){ x[j]=bf2f(v[j]); s+=x[j]; sq+=x[j]*x[j]; }
  #pragma unroll
  for (int mk=1; mk<64; mk<<=1){ s += __shfl_xor(s,mk); sq += __shfl_xor(sq,mk); }
  const float mean = s*(1.f/DMODEL);
  float var = sq*(1.f/DMODEL) - mean*mean;
  const float rstd = rsqrtf(var + 1e-5f);
  float* po = out + (size_t)row*DMODEL + lane*8;
  #pragma unroll
  for (int j=0;j<8;j++){
    const int c = lane*8+j;
    po[j] = (x[j]-mean)*rstd*gamma[c] + beta[c];
  }
}

extern "C" void kernel_launch(void* const* d_in, const int* in_sizes, int n_in,
                              void* d_out, int out_size, void* d_ws, size_t ws_size,
                              hipStream_t stream){
  (void)in_sizes; (void)n_in; (void)out_size; (void)ws_size;
  const float* q      = (const float*)d_in[0];
  const float* w_qkvs = (const float*)d_in[1];
  const float* fc_w   = (const float*)d_in[2];
  const float* fc_b   = (const float*)d_in[3];
  const float* ln_g   = (const float*)d_in[4];
  const float* ln_b   = (const float*)d_in[5];
  float* out = (float*)d_out;
  char* ws = (char*)d_ws;
  u16* x_rm  = (u16*)(ws);                 // [8192][512] bf16
  u16* kfb   = (u16*)(ws + 8388608);       // fragment-major K/Q tiles
  u16* vfb   = (u16*)(ws + 16777216);      // fragment-major V tiles
  u16* ao    = (u16*)(ws + 25165824);      // [8192][512]
  u16* wqkvb = (u16*)(ws + 33554432);
  u16* wfcb  = (u16*)(ws + 34078720);
  u16* y0    = kfb;                        // reuse after attention

  convert_k<<<128,256,0,stream>>>(w_qkvs, wqkvb, DMODEL*DMODEL);
  convert_k<<<128,256,0,stream>>>(fc_w,   wfcb,  DMODEL*DMODEL);
  transpose_f2b<<<dim3(8,16,BATCH),256,0,stream>>>(q, x_rm, DMODEL, LTOK);
  qkv_gemm<<<dim3(128,8),256,0,stream>>>(x_rm, wqkvb, kfb, vfb);
  attn_k<<<256,256,0,stream>>>(kfb, vfb, ao);
  fc_gemm<<<dim3(128,8),256,0,stream>>>(ao, wfcb, fc_b, x_rm, y0);
  ln_k<<<2048,256,0,stream>>>(y0, ln_g, ln_b, out);
}

// Round 10
// 77.477 us; speedup vs baseline: 2.1070x; 1.0541x over previous
//
#include <hip/hip_runtime.h>
#include <stdint.h>

#define BATCH 8
#define LTOK 1024
#define DMODEL 512
#define NHEAD 8
#define DHEAD 64

typedef unsigned short u16;
typedef u16 u16x8 __attribute__((ext_vector_type(8)));
typedef short bf16x8 __attribute__((ext_vector_type(8)));
typedef float f32x4 __attribute__((ext_vector_type(4)));

#define MFMA16(a,b,c) __builtin_amdgcn_mfma_f32_16x16x32_bf16((a),(b),(c),0,0,0)

__device__ __forceinline__ float bf2f(u16 x){
  union{unsigned u; float f;} v; v.u = ((unsigned)x)<<16; return v.f;
}
__device__ __forceinline__ u16 f2bf(float f){
  union{float f; unsigned u;} v; v.f = f;
  unsigned r = v.u + 0x7fffu + ((v.u>>16)&1u);
  return (u16)(r>>16);
}

__device__ __forceinline__ void gload_lds16(const u16* g, u16* l){
  __builtin_amdgcn_global_load_lds(
      (const __attribute__((address_space(1))) void*)g,
      (__attribute__((address_space(3))) void*)l,
      16, 0, 0);
}

// ---------------- fp32 -> bf16 elementwise convert ------------------------------
__global__ __launch_bounds__(256) void convert_k(const float* __restrict__ src,
                                                 u16* __restrict__ dst, int n){
  const int i = (blockIdx.x*256 + threadIdx.x)*8;
  if (i >= n) return;
  u16x8 v;
  #pragma unroll
  for (int j=0;j<8;j++) v[j] = f2bf(src[i+j]);
  *(u16x8*)(dst + i) = v;
}

// ---------------- 64x64 tiled transpose fp32->bf16: dst[c][r] = src[r][c] -------
__global__ __launch_bounds__(256) void transpose_f2b(const float* __restrict__ src,
                                                     u16* __restrict__ dst,
                                                     int R, int C){
  __shared__ __align__(16) u16 t[64][72];
  const int b  = blockIdx.z;
  const int r0 = blockIdx.x*64, c0 = blockIdx.y*64;
  const float* s = src + (size_t)b*R*C;
  u16* d         = dst + (size_t)b*R*C;
  const int tid = threadIdx.x;
  const int row = tid>>3, ch = (tid&7)*8;
  #pragma unroll
  for (int rr=0; rr<64; rr+=32){
    const float* p = s + (size_t)(r0+row+rr)*C + c0 + ch;
    u16x8 v;
    #pragma unroll
    for (int j=0;j<8;j++) v[j] = f2bf(p[j]);
    *(u16x8*)&t[row+rr][ch] = v;
  }
  __syncthreads();
  #pragma unroll
  for (int rr=0; rr<64; rr+=32){
    const int dr = row+rr;
    u16x8 v;
    #pragma unroll
    for (int j=0;j<8;j++) v[j] = t[ch+j][dr];
    *(u16x8*)(d + (size_t)(c0+dr)*R + r0 + ch) = v;
  }
}

// stage a 64x64 bf16 tile into linear LDS with the read-swizzle pre-applied to
// the source k-chunk (rule 21: filler granule (r, cc^(r&7)) holds A[r][cc*8])
__device__ __forceinline__ void stage_gemm(const u16* __restrict__ src,
                                           int row0, int k0, u16* lds, int tid){
  #pragma unroll
  for (int s2=0; s2<2; ++s2){
    const int slot = tid + s2*256;
    const int row = slot>>3, ch8 = slot&7;
    const int k = k0 + ((ch8 ^ (row&7))<<3);
    gload_lds16(src + (size_t)(row0+row)*DMODEL + k, lds + slot*8);
  }
}

// ---------------- QKV projection -> MFMA-fragment-major K/Q and V^T tiles -------
// Kf[bh][t][frag=ks*4+nj][lane=lg*16+lr][j]  holds K[t*64+nj*16+lr][ks*32+lg*8+j]
// Vf[bh][t][frag=ks*4+dj][lane=lg*16+lr][j]  holds V[t*64+ks*32+lg*8+j][dj*16+lr]
__global__ __launch_bounds__(256) void qkv_gemm(const u16* __restrict__ A,
                                                const u16* __restrict__ W,
                                                u16* __restrict__ Kf,
                                                u16* __restrict__ Vf){
  __shared__ __align__(128) u16 sA[2][4096];
  __shared__ __align__(128) u16 sB[2][4096];
  const int m0 = blockIdx.x*64, n0 = blockIdx.y*64;
  const int tid = threadIdx.x, w = tid>>6, lane = tid&63;
  const int wr = w>>1, wc = w&1;
  const int lr = lane&15, lg = lane>>4;
  f32x4 acc[2][2] = {};
  stage_gemm(A, m0, 0, sA[0], tid);
  stage_gemm(W, n0, 0, sB[0], tid);
  int buf = 0;
  for (int kt=0; kt<8; ++kt){
    __syncthreads();
    if (kt < 7){
      stage_gemm(A, m0, (kt+1)*64, sA[buf^1], tid);
      stage_gemm(W, n0, (kt+1)*64, sB[buf^1], tid);
    }
    #pragma unroll
    for (int ks=0; ks<2; ++ks){
      bf16x8 af[2], bfr[2];
      #pragma unroll
      for (int mi=0; mi<2; ++mi){
        const int r = wr*32 + mi*16 + lr;
        af[mi] = *(const bf16x8*)(&sA[buf][(r*64 + ks*32 + lg*8) ^ ((r&7)<<3)]);
      }
      #pragma unroll
      for (int nj=0; nj<2; ++nj){
        const int r = wc*32 + nj*16 + lr;
        bfr[nj] = *(const bf16x8*)(&sB[buf][(r*64 + ks*32 + lg*8) ^ ((r&7)<<3)]);
      }
      #pragma unroll
      for (int mi=0; mi<2; ++mi)
        #pragma unroll
        for (int nj=0; nj<2; ++nj)
          acc[mi][nj] = MFMA16(af[mi], bfr[nj], acc[mi][nj]);
    }
    buf ^= 1;
  }
  #pragma unroll
  for (int mi=0; mi<2; ++mi)
    #pragma unroll
    for (int nj=0; nj<2; ++nj)
      #pragma unroll
      for (int r=0; r<4; ++r){
        const int m = m0 + wr*32 + mi*16 + lg*4 + r;
        const int n = n0 + wc*32 + nj*16 + lr;
        const int bb = m>>10, l = m&1023, hh = n>>6, d = n&63;
        const int bh = bb*NHEAD + hh;
        const int t = l>>6;
        const u16 val = f2bf(acc[mi][nj][r]);
        {  // K/Q fragment position
          const int rr = l&63;
          const int fnj = rr>>4, flr = rr&15;
          const int fks = d>>5, flg = (d>>3)&3, fj = d&7;
          Kf[(size_t)(bh*16 + t)*4096 + (fks*4+fnj)*512 + (flg*16+flr)*8 + fj] = val;
        }
        {  // V fragment position
          const int ll = l&63;
          const int fks = ll>>5, flg = (ll>>3)&3, fj = ll&7;
          const int fdj = d>>4, flr = d&15;
          Vf[(size_t)(bh*16 + t)*4096 + (fks*4+fdj)*512 + (flg*16+flr)*8 + fj] = val;
        }
      }
}

// ---------------- attention: LDS-shared K/V dbuf, 32 q-rows/wave, 2 blk/CU ------
__global__ __launch_bounds__(256,2) void attn_k(const u16* __restrict__ kf,
                                                const u16* __restrict__ vf,
                                                u16* __restrict__ ao){
  __shared__ __align__(128) u16 sK[2][4096];
  __shared__ __align__(128) u16 sV[2][4096];
  __shared__ __align__(128) u16 sP[8192];     // 4 waves x 2 groups x 2KB
  const int bid = blockIdx.x;
  const int qq = bid >> 6, bh = bid & 63;     // XCD = bid%8 = bh%8 -> K/V L2-resident
  const int b = bh >> 3, h = bh & 7;
  const u16* Kf = kf + (size_t)bh*16*4096;
  const u16* Vf = vf + (size_t)bh*16*4096;
  const int tid = threadIdx.x, w = tid>>6, lane = tid&63;
  const int lr = lane&15, lg = lane>>4;
  const int qtile = qq*2 + (w>>1);            // this wave's 64-row tile
  const int g0 = (w&1)*2;                     // this wave's 2 nj-subtiles

  // Q fragments for 2 groups; pre-scaled by (1/8)*log2(e)
  bf16x8 aq[2][2];
  #pragma unroll
  for (int gg=0; gg<2; ++gg)
    #pragma unroll
    for (int ks=0; ks<2; ++ks){
      u16x8 v = *(const u16x8*)(Kf + (size_t)qtile*4096 + (ks*4+g0+gg)*512 + lane*8);
      bf16x8 t;
      #pragma unroll
      for (int j=0;j<8;j++) t[j] = (short)f2bf(bf2f(v[j])*0.18033688f);
      aq[gg][ks] = t;
    }

  f32x4 o[2][4] = {};
  float lsum[2][4] = {};

  // fragment-major tiles are linear: stage = straight 8KB copy, 16B/thread x2
  gload_lds16(Kf + tid*8,        sK[0] + tid*8);
  gload_lds16(Kf + 2048 + tid*8, sK[0] + 2048 + tid*8);
  gload_lds16(Vf + tid*8,        sV[0] + tid*8);
  gload_lds16(Vf + 2048 + tid*8, sV[0] + 2048 + tid*8);
  __syncthreads();

  int buf = 0;
  for (int kt=0; kt<16; ++kt){
    if (kt+1 < 16){
      const u16* Kn = Kf + (size_t)(kt+1)*4096;
      const u16* Vn = Vf + (size_t)(kt+1)*4096;
      gload_lds16(Kn + tid*8,        sK[buf^1] + tid*8);
      gload_lds16(Kn + 2048 + tid*8, sK[buf^1] + 2048 + tid*8);
      gload_lds16(Vn + tid*8,        sV[buf^1] + tid*8);
      gload_lds16(Vn + 2048 + tid*8, sV[buf^1] + 2048 + tid*8);
    }
    // K fragments once per wave, reused by both q-groups
    bf16x8 bk[2][4];
    #pragma unroll
    for (int ks=0; ks<2; ++ks)
      #pragma unroll
      for (int nj=0; nj<4; ++nj)
        bk[ks][nj] = *(const bf16x8*)(&sK[buf][(ks*4+nj)*512 + lane*8]);
    #pragma unroll
    for (int gg=0; gg<2; ++gg){
      f32x4 sc[4] = {};
      __builtin_amdgcn_s_setprio(1);
      #pragma unroll
      for (int ks=0; ks<2; ++ks)
        #pragma unroll
        for (int nj=0; nj<4; ++nj)
          sc[nj] = MFMA16(aq[gg][ks], bk[ks][nj], sc[nj]);
      __builtin_amdgcn_s_setprio(0);
      const int wp = (w*2+gg)*1024;
      #pragma unroll
      for (int nj=0; nj<4; ++nj){
        #pragma unroll
        for (int r=0; r<4; ++r){
          const float p = __builtin_amdgcn_exp2f(sc[nj][r]);
          const unsigned pu = __float_as_uint(p) & 0xFFFF0000u;
          lsum[gg][r] += __uint_as_float(pu);
          const int prow = lg*4 + r;
          sP[wp + ((prow*64 + nj*16 + lr) ^ ((prow&7)<<3))] = (u16)(pu>>16);
        }
      }
    }
    asm volatile("s_waitcnt lgkmcnt(0)" ::: "memory");
    // V fragments once per wave, reused by both q-groups
    bf16x8 bv[2][4];
    #pragma unroll
    for (int ks=0; ks<2; ++ks)
      #pragma unroll
      for (int dj=0; dj<4; ++dj)
        bv[ks][dj] = *(const bf16x8*)(&sV[buf][(ks*4+dj)*512 + lane*8]);
    __builtin_amdgcn_s_setprio(1);
    #pragma unroll
    for (int gg=0; gg<2; ++gg){
      const int wp = (w*2+gg)*1024;
      #pragma unroll
      for (int ks=0; ks<2; ++ks){
        bf16x8 pa = *(const bf16x8*)(&sP[wp + ((lr*64 + ks*32 + lg*8) ^ ((lr&7)<<3))]);
        #pragma unroll
        for (int dj=0; dj<4; ++dj)
          o[gg][dj] = MFMA16(pa, bv[ks][dj], o[gg][dj]);
      }
    }
    __builtin_amdgcn_s_setprio(0);
    __syncthreads();   // drains prefetch vmcnt + all lds reads of buf
    buf ^= 1;
  }

  // deferred row-sum reduce + write 32 rows
  #pragma unroll
  for (int gg=0; gg<2; ++gg){
    float inv[4];
    #pragma unroll
    for (int r=0; r<4; ++r){
      float s = lsum[gg][r];
      s += __shfl_xor(s,1); s += __shfl_xor(s,2);
      s += __shfl_xor(s,4); s += __shfl_xor(s,8);
      inv[r] = __builtin_amdgcn_rcpf(s);
    }
    const int i0 = qtile*64 + (g0+gg)*16;
    #pragma unroll
    for (int dj=0; dj<4; ++dj)
      #pragma unroll
      for (int r=0; r<4; ++r){
        const int l = i0 + lg*4 + r;
        const int d = dj*16 + lr;
        ao[((size_t)(b*LTOK + l))*DMODEL + h*DHEAD + d] = f2bf(o[gg][dj][r]*inv[r]);
      }
  }
}

// ---------------- FC projection + bias + residual -------------------------------
__global__ __launch_bounds__(256) void fc_gemm(const u16* __restrict__ A,
                                               const u16* __restrict__ W,
                                               const float* __restrict__ bias,
                                               const u16* __restrict__ resid,
                                               u16* __restrict__ Y){
  __shared__ __align__(128) u16 sA[2][4096];
  __shared__ __align__(128) u16 sB[2][4096];
  const int m0 = blockIdx.x*64, n0 = blockIdx.y*64;
  const int tid = threadIdx.x, w = tid>>6, lane = tid&63;
  const int wr = w>>1, wc = w&1;
  const int lr = lane&15, lg = lane>>4;
  f32x4 acc[2][2] = {};
  stage_gemm(A, m0, 0, sA[0], tid);
  stage_gemm(W, n0, 0, sB[0], tid);
  int buf = 0;
  for (int kt=0; kt<8; ++kt){
    __syncthreads();
    if (kt < 7){
      stage_gemm(A, m0, (kt+1)*64, sA[buf^1], tid);
      stage_gemm(W, n0, (kt+1)*64, sB[buf^1], tid);
    }
    #pragma unroll
    for (int ks=0; ks<2; ++ks){
      bf16x8 af[2], bfr[2];
      #pragma unroll
      for (int mi=0; mi<2; ++mi){
        const int r = wr*32 + mi*16 + lr;
        af[mi] = *(const bf16x8*)(&sA[buf][(r*64 + ks*32 + lg*8) ^ ((r&7)<<3)]);
      }
      #pragma unroll
      for (int nj=0; nj<2; ++nj){
        const int r = wc*32 + nj*16 + lr;
        bfr[nj] = *(const bf16x8*)(&sB[buf][(r*64 + ks*32 + lg*8) ^ ((r&7)<<3)]);
      }
      #pragma unroll
      for (int mi=0; mi<2; ++mi)
        #pragma unroll
        for (int nj=0; nj<2; ++nj)
          acc[mi][nj] = MFMA16(af[mi], bfr[nj], acc[mi][nj]);
    }
    buf ^= 1;
  }
  #pragma unroll
  for (int mi=0; mi<2; ++mi)
    #pragma unroll
    for (int nj=0; nj<2; ++nj)
      #pragma unroll
      for (int r=0; r<4; ++r){
        const int m = m0 + wr*32 + mi*16 + lg*4 + r;
        const int n = n0 + wc*32 + nj*16 + lr;
        const float val = acc[mi][nj][r] + bias[n] + bf2f(resid[(size_t)m*DMODEL+n]);
        Y[(size_t)m*DMODEL+n] = f2bf(val);
      }
}

// ---------------- LayerNorm over 512, one wave per row; fp32 out ----------------
__global__ __launch_bounds__(256) void ln_k(const u16* __restrict__ Y,
                                            const float* __restrict__ gamma,
                                            const float* __restrict__ beta,
                                            float* __restrict__ out){
  const int row = blockIdx.x*4 + (threadIdx.x>>6);
  const int lane = threadIdx.x&63;
  const u16* yr = Y + (size_t)row*DMODEL;
  u16x8 v = *(const u16x8*)(yr + lane*8);
  float x[8]; float s=0.f, sq=0.f;
  #pragma unroll
  for (int j=0;j<8;j++){ x[j]=bf2f(v[j]); s+=x[j]; sq+=x[j]*x[j]; }
  #pragma unroll
  for (int mk=1; mk<64; mk<<=1){ s += __shfl_xor(s,mk); sq += __shfl_xor(sq,mk); }
  const float mean = s*(1.f/DMODEL);
  float var = sq*(1.f/DMODEL) - mean*mean;
  const float rstd = rsqrtf(var + 1e-5f);
  float* po = out + (size_t)row*DMODEL + lane*8;
  #pragma unroll
  for (int j=0;j<8;j++){
    const int c = lane*8+j;
    po[j] = (x[j]-mean)*rstd*gamma[c] + beta[c];
  }
}

extern "C" void kernel_launch(void* const* d_in, const int* in_sizes, int n_in,
                              void* d_out, int out_size, void* d_ws, size_t ws_size,
                              hipStream_t stream){
  (void)in_sizes; (void)n_in; (void)out_size; (void)ws_size;
  const float* q      = (const float*)d_in[0];
  const float* w_qkvs = (const float*)d_in[1];
  const float* fc_w   = (const float*)d_in[2];
  const float* fc_b   = (const float*)d_in[3];
  const float* ln_g   = (const float*)d_in[4];
  const float* ln_b   = (const float*)d_in[5];
  float* out = (float*)d_out;
  char* ws = (char*)d_ws;
  u16* x_rm  = (u16*)(ws);                 // [8192][512] bf16
  u16* kfb   = (u16*)(ws + 8388608);       // fragment-major K/Q tiles
  u16* vfb   = (u16*)(ws + 16777216);      // fragment-major V tiles
  u16* ao    = (u16*)(ws + 25165824);      // [8192][512]
  u16* wqkvb = (u16*)(ws + 33554432);
  u16* wfcb  = (u16*)(ws + 34078720);
  u16* y0    = kfb;                        // reuse after attention

  convert_k<<<128,256,0,stream>>>(w_qkvs, wqkvb, DMODEL*DMODEL);
  convert_k<<<128,256,0,stream>>>(fc_w,   wfcb,  DMODEL*DMODEL);
  transpose_f2b<<<dim3(8,16,BATCH),256,0,stream>>>(q, x_rm, DMODEL, LTOK);
  qkv_gemm<<<dim3(128,8),256,0,stream>>>(x_rm, wqkvb, kfb, vfb);
  attn_k<<<512,256,0,stream>>>(kfb, vfb, ao);
  fc_gemm<<<dim3(128,8),256,0,stream>>>(ao, wfcb, fc_b, x_rm, y0);
  ln_k<<<2048,256,0,stream>>>(y0, ln_g, ln_b, out);
}